// Round 9
// baseline (198.259 us; speedup 1.0000x reference)
//
#include <hip/hip_runtime.h>
#include <stdint.h>

#define U 128
#define V 128
#define IN_STRIDE 512
#define OUT_STRIDE 512
#define W_STRIDE (8 * U * V) /* 131072 floats per expert */
#define NB 32768
#define NE 4
#define NT 4                 /* tiles per gemm block */

// Workspace layout (bytes)
#define WS_WSHUF 0           // 524288 ushorts (1 MB) shuffled bf16 weights
#define WS_CNT   1048576     // 4 uint per-expert cursors/counts (16 B)
#define WS_SORT  1048640     // 4 * 32768 ints (512 KB): region e at e*NB

typedef __bf16 bf16x8 __attribute__((ext_vector_type(8)));
typedef float f32x16 __attribute__((ext_vector_type(16)));
typedef unsigned int u32x4 __attribute__((ext_vector_type(4)));

static __device__ __forceinline__ unsigned short f2bf(float f) {
    unsigned int u = __builtin_bit_cast(unsigned int, f);
    u += 0x7FFFu + ((u >> 16) & 1u);   // round-to-nearest-even
    return (unsigned short)(u >> 16);
}

// ---------------------------------------------------------------------------
// prep (R8 layout, unchanged): weights fp32 -> bf16, 32x32x16 B-fragment order.
//   shorts offset = (((e*8+s)*4+nt)*8+kt)*512 + lane*8 + j
//   element = W[e][s][k = kt*16+(lane>>5)*8+j][n = nt*32+(lane&31)], segs 4..7 x0.5
// ---------------------------------------------------------------------------
__global__ void prep_kernel(const float* __restrict__ w, unsigned short* __restrict__ wshuf,
                            unsigned int* __restrict__ cnt) {
    if (blockIdx.x == 0 && threadIdx.x < NE) cnt[threadIdx.x] = 0u;
    int t = blockIdx.x * 256 + threadIdx.x;   // 0..65535
    int lane = t & 63;
    int kt = (t >> 6) & 7;
    int nt = (t >> 9) & 3;
    int s  = (t >> 11) & 7;
    int e  = (t >> 14) & 3;
    int kbase = kt * 16 + ((lane >> 5) << 3);
    int n = nt * 32 + (lane & 31);
    const float* src = w + (size_t)e * W_STRIDE + (size_t)s * (U * V) + n;
    float sc = (s >= 4) ? 0.5f : 1.0f;
    __attribute__((aligned(16))) unsigned short o[8];
#pragma unroll
    for (int j = 0; j < 8; j++) o[j] = f2bf(src[(size_t)(kbase + j) * V] * sc);
    *(u32x4*)(wshuf + (size_t)t * 8) = *(const u32x4*)o;
}

// ---------------------------------------------------------------------------
// scatter: bucket rows by expert (order within expert irrelevant).
// ---------------------------------------------------------------------------
__global__ void scatter_kernel(const int* __restrict__ wid, unsigned int* __restrict__ cnt,
                               int* __restrict__ sorted) {
    __shared__ unsigned int lcnt[NE];
    __shared__ unsigned int lbase[NE];
    int t = threadIdx.x;
    if (t < NE) lcnt[t] = 0u;
    __syncthreads();
    int i = blockIdx.x * 256 + t;
    int e = wid[i];
    unsigned int lpos = atomicAdd(&lcnt[e], 1u);
    __syncthreads();
    if (t < NE) lbase[t] = atomicAdd(&cnt[t], lcnt[t]);
    __syncthreads();
    sorted[e * NB + (int)(lbase[e] + lpos)] = i;
}

// ---------------------------------------------------------------------------
// gemm R12: counted-vmcnt DMA pipeline with vmcnt-CLEAN compute.
// Evidence: R8/R11 2-phase blocks convoy (HBM duty 38-43%); R10's pipeline
// failed because gates drained stores and B-loads drained the prefetch.
// R12: 256 blocks x 512 thr (1 block/CU, LDS 128 KB), block = 128 sorted
// rows = 4 tiles x 32 rows, all 4 kouts (x read ONCE). Invariants:
//  (1) compute touches NO vmem: all 32 B-frags/wave (128 VGPR) loaded BEFORE
//      the DMAs and PINNED with asm(""::"v"(..)) so the compiler can't sink
//      them (R8/R11 showed it sinks read-only loads past barriers: VGPR=60).
//      B is expert-constant across tiles -> loaded once; reloaded only on
//      expert change (<=3 blocks), issued BEFORE that tile's DMAs.
//  (2) gates never drain the pipe: per iter the vmem queue is
//      [stores(T-1)<=32][DMA(T+1)x8][stores(T)x32]; gate = vmcnt(32) +
//      raw s_barrier -> retires exactly the DMAs, stores stay in flight.
// Per tile: 64 KB read + 64 KB write = 13.1K cyc at the 10 B/cy per-CU HBM
// share; DMAs are in flight during every compute window -> ~roofline.
// Staging/swizzle/compute/epilogue = R8 verbatim (verified): source-side XOR
// chunk swizzle, 32x32x16 MFMA, wave w = (kout=w>>1, nhalf=w&1).
// Masked 4-expert path for mixed tiles (<=3 globally; drains pipe, rare).
// ---------------------------------------------------------------------------
__global__ __launch_bounds__(512, 2) void gemm_kernel(
        const float* __restrict__ x, const unsigned short* __restrict__ wshuf,
        const unsigned int* __restrict__ cnt, const int* __restrict__ sorted,
        float* __restrict__ out) {
    const int blk = blockIdx.x;
    __shared__ float ldsf[2][32][512];   // 128 KB double buffer
    __shared__ int rowid[128];

    const unsigned int p1 = cnt[0];
    const unsigned int p2 = p1 + cnt[1];
    const unsigned int p3 = p2 + cnt[2];

    const int t = threadIdx.x;
    const int w = t >> 6, lane = t & 63;
    const int l5 = lane >> 5, m0 = lane & 31;
    const int kout = w >> 1, nhalf = w & 1;
    const int rsw = m0 & 7;
    const int xb1 = (kout + 3) & 3;

#define EXPERT_OF(ls) (((ls) >= p1) + ((ls) >= p2) + ((ls) >= p3))
#define PREFIX_OF(e)  ((e) == 0 ? 0u : (e) == 1 ? p1 : (e) == 2 ? p2 : p3)

    // ---- rowid for all 128 rows of this block ----
    if (t < 128) {
        unsigned int ls = (unsigned int)(blk * 128 + t);
        int e = EXPERT_OF(ls);
        rowid[t] = sorted[e * NB + (int)(ls - PREFIX_OF(e))];
    }

    u32x4 bp[32];   // 32 B-frags: bp[c*16 + kt*2 + n01], nt = nhalf*2 + n01

#define LOADB(eu) do { \
    _Pragma("unroll") \
    for (int c_ = 0; c_ < 2; c_++) { \
        const int sg_ = c_ ? (xb1 + 4) : kout; \
        const unsigned short* wb_ = wshuf + \
            (size_t)((((eu) * 8 + sg_) * 4 + nhalf * 2) * 8) * 512 + (size_t)lane * 8; \
        _Pragma("unroll") \
        for (int kt_ = 0; kt_ < 8; kt_++) { \
            bp[c_ * 16 + kt_ * 2]     = *(const u32x4*)(wb_ + (size_t)kt_ * 512); \
            bp[c_ * 16 + kt_ * 2 + 1] = *(const u32x4*)(wb_ + (size_t)(8 + kt_) * 512); \
        } \
    } \
} while (0)

#define PINB() do { \
    asm volatile("" :: "v"(bp[0]),  "v"(bp[1]),  "v"(bp[2]),  "v"(bp[3])); \
    asm volatile("" :: "v"(bp[4]),  "v"(bp[5]),  "v"(bp[6]),  "v"(bp[7])); \
    asm volatile("" :: "v"(bp[8]),  "v"(bp[9]),  "v"(bp[10]), "v"(bp[11])); \
    asm volatile("" :: "v"(bp[12]), "v"(bp[13]), "v"(bp[14]), "v"(bp[15])); \
    asm volatile("" :: "v"(bp[16]), "v"(bp[17]), "v"(bp[18]), "v"(bp[19])); \
    asm volatile("" :: "v"(bp[20]), "v"(bp[21]), "v"(bp[22]), "v"(bp[23])); \
    asm volatile("" :: "v"(bp[24]), "v"(bp[25]), "v"(bp[26]), "v"(bp[27])); \
    asm volatile("" :: "v"(bp[28]), "v"(bp[29]), "v"(bp[30]), "v"(bp[31])); \
} while (0)

    // ---- prologue: B for tile 0's expert (if uniform), then DMA tile 0 ----
    const unsigned int rb0 = (unsigned int)(blk * 128);
    const int e0h = EXPERT_OF(rb0), e0t = EXPERT_OF(rb0 + 31u);
    int ecur = -1;
    if (e0h == e0t) { LOADB(e0h); ecur = e0h; PINB(); }

#pragma unroll
    for (int i = 0; i < 4; i++) {
        int r = 4 * w + i;
        unsigned int ls = (unsigned int)(blk * 128 + r);
        int e = EXPERT_OF(ls);
        int rr = sorted[e * NB + (int)(ls - PREFIX_OF(e))];
        int rs = r & 7;
        const float* xb = x + (size_t)rr * IN_STRIDE + ((m0 ^ rs) << 2) + l5 * 128;
        __builtin_amdgcn_global_load_lds(
            (const __attribute__((address_space(1))) unsigned int*)xb,
            (__attribute__((address_space(3))) unsigned int*)&ldsf[0][r][0], 16, 0, 0);
        __builtin_amdgcn_global_load_lds(
            (const __attribute__((address_space(1))) unsigned int*)(xb + 256),
            (__attribute__((address_space(3))) unsigned int*)&ldsf[0][r][256], 16, 0, 0);
    }

    asm volatile("s_waitcnt vmcnt(0) lgkmcnt(0)" ::: "memory");
    __builtin_amdgcn_sched_barrier(0);
    __builtin_amdgcn_s_barrier();
    __builtin_amdgcn_sched_barrier(0);

    const int colb = kout * 128 + nhalf * 64 + m0;
    const int rh = l5 << 2;

    for (int T = 0; T < NT; T++) {
        const unsigned int rb = (unsigned int)(blk * 128 + T * 32);
        const int eh = EXPERT_OF(rb), et = EXPERT_OF(rb + 31u);
        const int fast = (eh == et);
        const float (*buf)[512] = ldsf[T & 1];

        // B reload on expert change, BEFORE this iteration's DMAs
        if (fast && eh != ecur) { LOADB(eh); ecur = eh; PINB(); }

        // ---- DMA tile T+1 (into the buffer tile T-1 used) ----
        if (T < NT - 1) {
#pragma unroll
            for (int i = 0; i < 4; i++) {
                int r = 4 * w + i;
                int rr = rowid[(T + 1) * 32 + r];
                int rs = r & 7;
                const float* xb = x + (size_t)rr * IN_STRIDE + ((m0 ^ rs) << 2) + l5 * 128;
                __builtin_amdgcn_global_load_lds(
                    (const __attribute__((address_space(1))) unsigned int*)xb,
                    (__attribute__((address_space(3))) unsigned int*)&ldsf[(T + 1) & 1][r][0], 16, 0, 0);
                __builtin_amdgcn_global_load_lds(
                    (const __attribute__((address_space(1))) unsigned int*)(xb + 256),
                    (__attribute__((address_space(3))) unsigned int*)&ldsf[(T + 1) & 1][r][256], 16, 0, 0);
            }
        }

        f32x16 acc0 = {}, acc1 = {};

        if (fast) {
            // ---- compute: ds_read + registers only (NO vmem) ----
#pragma unroll
            for (int c = 0; c < 2; c++) {
                const float* ar = &buf[m0][(c ? xb1 : kout) * 128];
#pragma unroll
                for (int kt = 0; kt < 8; kt++) {
                    int gj0 = kt * 4 + l5 * 2;
                    float4 va = *(const float4*)(ar + ((gj0 ^ rsw) << 2));
                    float4 vb = *(const float4*)(ar + (((gj0 + 1) ^ rsw) << 2));
                    bf16x8 a;
                    a[0] = (__bf16)va.x; a[1] = (__bf16)va.y;
                    a[2] = (__bf16)va.z; a[3] = (__bf16)va.w;
                    a[4] = (__bf16)vb.x; a[5] = (__bf16)vb.y;
                    a[6] = (__bf16)vb.z; a[7] = (__bf16)vb.w;
                    bf16x8 b0 = __builtin_bit_cast(bf16x8, bp[c * 16 + kt * 2]);
                    bf16x8 b1 = __builtin_bit_cast(bf16x8, bp[c * 16 + kt * 2 + 1]);
                    acc0 = __builtin_amdgcn_mfma_f32_32x32x16_bf16(a, b0, acc0, 0, 0, 0);
                    acc1 = __builtin_amdgcn_mfma_f32_32x32x16_bf16(a, b1, acc1, 0, 0, 0);
                }
            }
        } else {
            // ---- mixed tile (<=3 globally): masked 4-expert path ----
            const unsigned int l0 = rb + (unsigned int)m0;
            const int e0 = EXPERT_OF(l0);
            unsigned int msk[4];
#pragma unroll
            for (int e = 0; e < 4; e++) msk[e] = (e0 == e) ? 0xFFFFFFFFu : 0u;
            const int xbs[2] = {kout, xb1};
            const int sgs[2] = {kout, xb1 + 4};
#pragma unroll
            for (int c = 0; c < 2; c++) {
                const float* ar = &buf[m0][xbs[c] * 128];
#pragma unroll
                for (int kt = 0; kt < 8; kt++) {
                    int gj0 = kt * 4 + l5 * 2;
                    float4 va = *(const float4*)(ar + ((gj0 ^ rsw) << 2));
                    float4 vb = *(const float4*)(ar + (((gj0 + 1) ^ rsw) << 2));
                    __attribute__((aligned(16))) unsigned short au[8];
                    au[0] = f2bf(va.x); au[1] = f2bf(va.y);
                    au[2] = f2bf(va.z); au[3] = f2bf(va.w);
                    au[4] = f2bf(vb.x); au[5] = f2bf(vb.y);
                    au[6] = f2bf(vb.z); au[7] = f2bf(vb.w);
                    u32x4 araw = *(const u32x4*)au;
#pragma unroll
                    for (int e = 0; e < 4; e++) {
                        u32x4 mm = {msk[e], msk[e], msk[e], msk[e]};
                        bf16x8 am = __builtin_bit_cast(bf16x8, araw & mm);
                        const unsigned short* wbe = wshuf +
                            (size_t)(((e * 8 + sgs[c]) * 4 + nhalf * 2) * 8) * 512 + (size_t)lane * 8;
                        bf16x8 b0 = __builtin_bit_cast(bf16x8, *(const u32x4*)(wbe + (size_t)kt * 512));
                        bf16x8 b1 = __builtin_bit_cast(bf16x8, *(const u32x4*)(wbe + (size_t)(8 + kt) * 512));
                        acc0 = __builtin_amdgcn_mfma_f32_32x32x16_bf16(am, b0, acc0, 0, 0, 0);
                        acc1 = __builtin_amdgcn_mfma_f32_32x32x16_bf16(am, b1, acc1, 0, 0, 0);
                    }
                }
            }
        }

        // ---- stores of tile T (fire-and-forget; capped by next gate) ----
#pragma unroll
        for (int q = 0; q < 4; q++)
#pragma unroll
            for (int d = 0; d < 4; d++) {
                int reg = q * 4 + d;
                int rl = d + 8 * q + rh;
                float* o = out + (size_t)rowid[T * 32 + rl] * OUT_STRIDE + colb;
                o[0]  = acc0[reg];
                o[32] = acc1[reg];
            }

        // ---- gate: retire DMA(T+1), keep the 32 stores in flight ----
        if (T < NT - 1) {
            asm volatile("s_waitcnt vmcnt(32)" ::: "memory");
            __builtin_amdgcn_sched_barrier(0);
            __builtin_amdgcn_s_barrier();
            __builtin_amdgcn_sched_barrier(0);
        }
    }
#undef LOADB
#undef PINB
#undef EXPERT_OF
#undef PREFIX_OF
}

extern "C" void kernel_launch(void* const* d_in, const int* in_sizes, int n_in,
                              void* d_out, int out_size, void* d_ws, size_t ws_size,
                              hipStream_t stream) {
    const float* x = (const float*)d_in[0];
    const float* w = (const float*)d_in[1];
    const int* wid = (const int*)d_in[2];
    float* out = (float*)d_out;

    unsigned short* wshuf = (unsigned short*)((char*)d_ws + WS_WSHUF);
    unsigned int* cnt = (unsigned int*)((char*)d_ws + WS_CNT);
    int* sorted = (int*)((char*)d_ws + WS_SORT);

    prep_kernel<<<256, 256, 0, stream>>>(w, wshuf, cnt);
    scatter_kernel<<<128, 256, 0, stream>>>(wid, cnt, sorted);
    gemm_kernel<<<256, 512, 0, stream>>>(x, wshuf, cnt, sorted, out);
}

// Round 10
// 137.385 us; speedup vs baseline: 1.4431x; 1.4431x over previous
//
#include <hip/hip_runtime.h>
#include <stdint.h>

#define U 128
#define V 128
#define IN_STRIDE 512
#define OUT_STRIDE 512
#define W_STRIDE (8 * U * V) /* 131072 floats per expert */
#define NB 32768
#define NE 4

// Workspace layout (bytes)
#define WS_WSHUF 0           // 524288 ushorts (1 MB) shuffled bf16 weights
#define WS_CNT   1048576     // 4 uint per-expert cursors/counts (16 B)
#define WS_SORT  1048640     // 4 * 32768 ints (512 KB): region e at e*NB

typedef __bf16 bf16x8 __attribute__((ext_vector_type(8)));
typedef float f32x16 __attribute__((ext_vector_type(16)));
typedef unsigned int u32x4 __attribute__((ext_vector_type(4)));

static __device__ __forceinline__ unsigned short f2bf(float f) {
    unsigned int u = __builtin_bit_cast(unsigned int, f);
    u += 0x7FFFu + ((u >> 16) & 1u);   // round-to-nearest-even
    return (unsigned short)(u >> 16);
}

// ---------------------------------------------------------------------------
// fused prep+scatter (cnt pre-zeroed by hipMemsetAsync, stream-ordered).
// prep: weights fp32 -> bf16, 32x32x16 B-fragment layout (R8 verbatim):
//   shorts offset = (((e*8+s)*4+nt)*8+kt)*512 + lane*8 + j
//   element = W[e][s][k = kt*16+(lane>>5)*8+j][n = nt*32+(lane&31)], segs 4..7 x0.5
// scatter (blocks 0..127 only): bucket rows by expert; two-level atomics.
// ---------------------------------------------------------------------------
__global__ void prep_scatter_kernel(const float* __restrict__ w,
                                    unsigned short* __restrict__ wshuf,
                                    const int* __restrict__ wid,
                                    unsigned int* __restrict__ cnt,
                                    int* __restrict__ sorted) {
    const int bid = blockIdx.x;
    const int tid = threadIdx.x;

    // ---- prep part (all 256 blocks) ----
    {
        int t = bid * 256 + tid;   // 0..65535
        int lane = t & 63;
        int kt = (t >> 6) & 7;
        int nt = (t >> 9) & 3;
        int s  = (t >> 11) & 7;
        int e  = (t >> 14) & 3;
        int kbase = kt * 16 + ((lane >> 5) << 3);
        int n = nt * 32 + (lane & 31);
        const float* src = w + (size_t)e * W_STRIDE + (size_t)s * (U * V) + n;
        float sc = (s >= 4) ? 0.5f : 1.0f;
        __attribute__((aligned(16))) unsigned short o[8];
#pragma unroll
        for (int j = 0; j < 8; j++) o[j] = f2bf(src[(size_t)(kbase + j) * V] * sc);
        *(u32x4*)(wshuf + (size_t)t * 8) = *(const u32x4*)o;
    }

    // ---- scatter part (blocks 0..127; block-uniform branch, barriers legal) ----
    if (bid < 128) {
        __shared__ unsigned int lcnt[NE];
        __shared__ unsigned int lbase[NE];
        if (tid < NE) lcnt[tid] = 0u;
        __syncthreads();
        int i = bid * 256 + tid;
        int e = wid[i];
        unsigned int lpos = atomicAdd(&lcnt[e], 1u);
        __syncthreads();
        if (tid < NE) lbase[tid] = atomicAdd(&cnt[tid], lcnt[tid]);
        __syncthreads();
        sorted[e * NB + (int)(lbase[e] + lpos)] = i;
    }
}

// ---------------------------------------------------------------------------
// gemm R13 = R8 chassis (best measured: 44us) + truly-pinned c0 B-preload.
// R8: 1024 blocks x 512 thr, 32-row sorted tile, LDS [32][512] fp32 (64 KB,
// 2 blocks/CU, 16 waves/CU), global_load_lds staging, ONE barrier, dense
// epilogue (WRITE stays exactly 64 MB). R8's flaw (VGPR_Count=60): the
// compiler SANK the B-preload into the compute loop (input-only asm pins
// don't work: read-only wshuf loads are rematerializable). Fix: pin bp[]
// with "+v" read-WRITE asm constraints -- compiler must assume the register
// was modified, so uses after the barrier cannot be re-loaded from memory.
// Compute phase c0 = ds_read + MFMA only; c1's B inline (hides under c0).
// Swizzle (rule #21 both-sides): stage source chunk (m0^ (r&7)), fragment
// read XORs back; residual 4-way bank conflict structural (~1M cyc, ~2us).
// Fast single-expert path; masked 4-expert path for <=3 boundary tiles.
// ---------------------------------------------------------------------------
__global__ __launch_bounds__(512, 4) void gemm_kernel(
        const float* __restrict__ x, const unsigned short* __restrict__ wshuf,
        const unsigned int* __restrict__ cnt, const int* __restrict__ sorted,
        float* __restrict__ out) {
    const int rowbase = blockIdx.x * 32;
    __shared__ float ldsf[32][512];   // 64 KB
    __shared__ int rowid[32];

    const unsigned int p1 = cnt[0];
    const unsigned int p2 = p1 + cnt[1];
    const unsigned int p3 = p2 + cnt[2];

    const int t = threadIdx.x;
    const int w = t >> 6, lane = t & 63;
    const int l5 = lane >> 5, m0 = lane & 31;
    const int kout = w >> 1, nhalf = w & 1;

    // ---- row ids for this wave's 4 staged rows (rows 4w..4w+3) ----
    int rid[4];
#pragma unroll
    for (int i = 0; i < 4; i++) {
        unsigned int ls = (unsigned int)(rowbase + 4 * w + i);
        int e = (ls >= p1) + (ls >= p2) + (ls >= p3);
        unsigned int pe = (e == 0) ? 0u : (e == 1) ? p1 : (e == 2) ? p2 : p3;
        rid[i] = sorted[e * NB + (int)(ls - pe)];
    }
    if (t < 32) {
        unsigned int ls = (unsigned int)(rowbase + t);
        int e = (ls >= p1) + (ls >= p2) + (ls >= p3);
        unsigned int pe = (e == 0) ? 0u : (e == 1) ? p1 : (e == 2) ? p2 : p3;
        rowid[t] = sorted[e * NB + (int)(ls - pe)];
    }

    // ---- stage: 4 rows x 2 half-row DMAs, fire-and-forget ----
#pragma unroll
    for (int i = 0; i < 4; i++) {
        int r = 4 * w + i;
        int rs = r & 7;
        const float* xb = x + (size_t)rid[i] * IN_STRIDE + ((m0 ^ rs) << 2) + l5 * 128;
#pragma unroll
        for (int h = 0; h < 2; h++) {
            __builtin_amdgcn_global_load_lds(
                (const __attribute__((address_space(1))) unsigned int*)(xb + h * 256),
                (__attribute__((address_space(3))) unsigned int*)&ldsf[r][h * 256],
                16, 0, 0);
        }
    }

    // expert span / per-lane expert
    const unsigned int lh = (unsigned int)rowbase, lt = (unsigned int)(rowbase + 31);
    const int ehead = (lh >= p1) + (lh >= p2) + (lh >= p3);
    const int etail = (lt >= p1) + (lt >= p2) + (lt >= p3);
    const unsigned int l0 = (unsigned int)(rowbase + m0);
    const int e0 = (l0 >= p1) + (l0 >= p2) + (l0 >= p3);

    const int xbc1 = (kout + 3) & 3;
    const int xbs[2] = {kout, xbc1};
    const int sgs[2] = {kout, xbc1 + 4};
    const int rsw = m0 & 7;

    f32x16 acc0 = {}, acc1 = {};

    if (ehead == etail) {
        // ---- fast path: whole 32-row tile is one expert ----
        // preload ALL 16 c0 B-frags; "+v" pins survive the barrier.
        const unsigned short* wb0 =
            wshuf + (size_t)(((ehead * 8 + sgs[0]) * 4 + nhalf * 2) * 8) * 512 + (size_t)lane * 8;
        u32x4 bp[16];
#pragma unroll
        for (int kt = 0; kt < 8; kt++) {
            bp[kt * 2]     = *(const u32x4*)(wb0 + (size_t)kt * 512);
            bp[kt * 2 + 1] = *(const u32x4*)(wb0 + (size_t)(8 + kt) * 512);
        }
        asm volatile("" : "+v"(bp[0]), "+v"(bp[1]), "+v"(bp[2]), "+v"(bp[3]),
                          "+v"(bp[4]), "+v"(bp[5]), "+v"(bp[6]), "+v"(bp[7]));
        asm volatile("" : "+v"(bp[8]),  "+v"(bp[9]),  "+v"(bp[10]), "+v"(bp[11]),
                          "+v"(bp[12]), "+v"(bp[13]), "+v"(bp[14]), "+v"(bp[15]));

        __syncthreads();   // drains x-DMAs (and the B-preload returns)

        // ---- compute c0: ds_read + registers only ----
        {
            const float* ar = &ldsf[m0][kout * 128];
#pragma unroll
            for (int kt = 0; kt < 8; kt++) {
                int gj0 = kt * 4 + l5 * 2;
                float4 va = *(const float4*)(ar + ((gj0 ^ rsw) << 2));
                float4 vb = *(const float4*)(ar + (((gj0 + 1) ^ rsw) << 2));
                bf16x8 a;
                a[0] = (__bf16)va.x; a[1] = (__bf16)va.y;
                a[2] = (__bf16)va.z; a[3] = (__bf16)va.w;
                a[4] = (__bf16)vb.x; a[5] = (__bf16)vb.y;
                a[6] = (__bf16)vb.z; a[7] = (__bf16)vb.w;
                bf16x8 b0 = __builtin_bit_cast(bf16x8, bp[kt * 2]);
                bf16x8 b1 = __builtin_bit_cast(bf16x8, bp[kt * 2 + 1]);
                acc0 = __builtin_amdgcn_mfma_f32_32x32x16_bf16(a, b0, acc0, 0, 0, 0);
                acc1 = __builtin_amdgcn_mfma_f32_32x32x16_bf16(a, b1, acc1, 0, 0, 0);
            }
        }
        // ---- compute c1: B inline (L2 latency hides under c0's MFMAs) ----
        {
            const unsigned short* wb1 =
                wshuf + (size_t)(((ehead * 8 + sgs[1]) * 4 + nhalf * 2) * 8) * 512 + (size_t)lane * 8;
            const float* ar = &ldsf[m0][xbc1 * 128];
#pragma unroll
            for (int kt = 0; kt < 8; kt++) {
                int gj0 = kt * 4 + l5 * 2;
                float4 va = *(const float4*)(ar + ((gj0 ^ rsw) << 2));
                float4 vb = *(const float4*)(ar + (((gj0 + 1) ^ rsw) << 2));
                bf16x8 a;
                a[0] = (__bf16)va.x; a[1] = (__bf16)va.y;
                a[2] = (__bf16)va.z; a[3] = (__bf16)va.w;
                a[4] = (__bf16)vb.x; a[5] = (__bf16)vb.y;
                a[6] = (__bf16)vb.z; a[7] = (__bf16)vb.w;
                bf16x8 b0 = __builtin_bit_cast(bf16x8, *(const u32x4*)(wb1 + (size_t)kt * 512));
                bf16x8 b1 = __builtin_bit_cast(bf16x8, *(const u32x4*)(wb1 + (size_t)(8 + kt) * 512));
                acc0 = __builtin_amdgcn_mfma_f32_32x32x16_bf16(a, b0, acc0, 0, 0, 0);
                acc1 = __builtin_amdgcn_mfma_f32_32x32x16_bf16(a, b1, acc1, 0, 0, 0);
            }
        }
    } else {
        // ---- boundary tile (<=3 of 1024): masked 4-expert path ----
        unsigned int msk[4];
#pragma unroll
        for (int e = 0; e < 4; e++) msk[e] = (e0 == e) ? 0xFFFFFFFFu : 0u;
        __syncthreads();
#pragma unroll
        for (int c = 0; c < 2; c++) {
            const float* ar = &ldsf[m0][xbs[c] * 128];
#pragma unroll
            for (int kt = 0; kt < 8; kt++) {
                int gj0 = kt * 4 + l5 * 2;
                float4 va = *(const float4*)(ar + ((gj0 ^ rsw) << 2));
                float4 vb = *(const float4*)(ar + (((gj0 + 1) ^ rsw) << 2));
                __attribute__((aligned(16))) unsigned short au[8];
                au[0] = f2bf(va.x); au[1] = f2bf(va.y);
                au[2] = f2bf(va.z); au[3] = f2bf(va.w);
                au[4] = f2bf(vb.x); au[5] = f2bf(vb.y);
                au[6] = f2bf(vb.z); au[7] = f2bf(vb.w);
                u32x4 araw = *(const u32x4*)au;
#pragma unroll
                for (int e = 0; e < 4; e++) {
                    u32x4 mm = {msk[e], msk[e], msk[e], msk[e]};
                    bf16x8 am = __builtin_bit_cast(bf16x8, araw & mm);
                    const unsigned short* wbe =
                        wshuf + (size_t)(((e * 8 + sgs[c]) * 4 + nhalf * 2) * 8) * 512 + (size_t)lane * 8;
                    bf16x8 b0 = __builtin_bit_cast(bf16x8, *(const u32x4*)(wbe + (size_t)kt * 512));
                    bf16x8 b1 = __builtin_bit_cast(bf16x8, *(const u32x4*)(wbe + (size_t)(8 + kt) * 512));
                    acc0 = __builtin_amdgcn_mfma_f32_32x32x16_bf16(am, b0, acc0, 0, 0, 0);
                    acc1 = __builtin_amdgcn_mfma_f32_32x32x16_bf16(am, b1, acc1, 0, 0, 0);
                }
            }
        }
    }

    // ---- epilogue (dense, single burst -> full-line L2 writes, 64 MB) ----
    // C/D layout col=lane&31, row=(reg&3)+8*(reg>>2)+4*(lane>>5)
    const int colb = kout * 128 + nhalf * 64 + m0;
    const int rh = l5 << 2;
#pragma unroll
    for (int q = 0; q < 4; q++) {
#pragma unroll
        for (int d = 0; d < 4; d++) {
            int reg = q * 4 + d;
            int rl = d + 8 * q + rh;
            float* o = out + (size_t)rowid[rl] * OUT_STRIDE + colb;
            o[0]  = acc0[reg];
            o[32] = acc1[reg];
        }
    }
}

extern "C" void kernel_launch(void* const* d_in, const int* in_sizes, int n_in,
                              void* d_out, int out_size, void* d_ws, size_t ws_size,
                              hipStream_t stream) {
    const float* x = (const float*)d_in[0];
    const float* w = (const float*)d_in[1];
    const int* wid = (const int*)d_in[2];
    float* out = (float*)d_out;

    unsigned short* wshuf = (unsigned short*)((char*)d_ws + WS_WSHUF);
    unsigned int* cnt = (unsigned int*)((char*)d_ws + WS_CNT);
    int* sorted = (int*)((char*)d_ws + WS_SORT);

    hipMemsetAsync(cnt, 0, NE * sizeof(unsigned int), stream);
    prep_scatter_kernel<<<256, 256, 0, stream>>>(w, wshuf, wid, cnt, sorted);
    gemm_kernel<<<1024, 512, 0, stream>>>(x, wshuf, cnt, sorted, out);
}